// Round 9
// baseline (277.712 us; speedup 1.0000x reference)
//
#include <hip/hip_runtime.h>
#include <math.h>

#define D 128
#define H 8
#define C 16
#define NEG_SLOPE 0.2f
#define SCAN_TILE 1024  // elements per scan block (256 thr x 4)

typedef unsigned short ushortT;
typedef __attribute__((ext_vector_type(8))) short short8;
typedef __attribute__((ext_vector_type(4))) float f32x4;

// bf16 <-> f32 helpers (RNE pack; no NaN inputs here)
__device__ __forceinline__ float bf2f(unsigned short v) {
    union { unsigned int i; float f; } c;
    c.i = ((unsigned int)v) << 16;
    return c.f;
}
__device__ __forceinline__ unsigned short f2bf(float f) {
    union { float f; unsigned int i; } c;
    c.f = f;
    unsigned int lsb = (c.i >> 16) & 1u;
    c.i += 0x7fffu + lsb;
    return (unsigned short)(c.i >> 16);
}

// A-frag address for element (row r, col k):
// wt=r>>4, m=r&15, kt=k>>5, quad=(k>>3)&3, j=k&7, lane=m+16*quad
// addr = ((wt*4+kt)*64 + lane)*8 + j     (2048 ushorts per 16x128 tile)

// ---------------- CSR build (by dst; self-loop LAST; pad to x4 w/ sentinel) ----

// histogram (int4-vectorized); cursor starts at 0 (memsetAsync);
// atomic return value = edge's within-segment rank (0..cnt-1)
__global__ void k_hist(const int* __restrict__ ei, int* cursor,
                       int* __restrict__ rank, int E, int n) {
    int i4 = (blockIdx.x * blockDim.x + threadIdx.x) * 4;
    if (((E & 3) == 0) && i4 + 3 < E) {
        int4 dv = *(const int4*)(ei + (size_t)E + i4);
        int4 r;
        r.x = atomicAdd(cursor + dv.x, 1);
        r.y = atomicAdd(cursor + dv.y, 1);
        r.z = atomicAdd(cursor + dv.z, 1);
        r.w = atomicAdd(cursor + dv.w, 1);
        *(int4*)(rank + i4) = r;
    } else {
        for (int k = i4; k < E && k < i4 + 4; k++)
            rank[k] = atomicAdd(cursor + ei[(size_t)E + k], 1);
    }
}

// padded count per node = (cnt + 1 self-loop + 3) & ~3  (>= 4, multiple of 4)
__device__ __forceinline__ int padc(int c) { return (c + 4) & ~3; }

__global__ __launch_bounds__(256) void k_scan_partial(
    const int* __restrict__ cursor, int* __restrict__ bsum, int n) {
    __shared__ int lds[256];
    int t = threadIdx.x;
    int base = blockIdx.x * SCAN_TILE + t * 4;
    int s = 0;
    if (base + 3 < n) {
        int4 v = *(const int4*)(cursor + base);
        s = padc(v.x) + padc(v.y) + padc(v.z) + padc(v.w);
    } else {
        for (int k = 0; k < 4; k++)
            if (base + k < n) s += padc(cursor[base + k]);
    }
    lds[t] = s;
    __syncthreads();
    for (int st = 128; st > 0; st >>= 1) {
        if (t < st) lds[t] += lds[t + st];
        __syncthreads();
    }
    if (t == 0) bsum[blockIdx.x] = lds[0];
}

__global__ void k_scan_bsum(int* bsum, int nb) {
    if (threadIdx.x == 0 && blockIdx.x == 0) {
        int run = 0;
        for (int i = 0; i < nb; i++) {
            int v = bsum[i];
            bsum[i] = run;
            run += v;
        }
    }
}

// scan_final also places self-loops + sentinel pads (has cnt & segment start)
__global__ __launch_bounds__(256) void k_scan_final(
    const int* __restrict__ cursor, int* __restrict__ poffs,
    const int* __restrict__ bsum, int* __restrict__ csrsrc, int n) {
    __shared__ int lds[256];
    int t = threadIdx.x;
    int base = blockIdx.x * SCAN_TILE + t * 4;
    int c[4] = {0, 0, 0, 0};
    if (base + 3 < n) {
        int4 q = *(const int4*)(cursor + base);
        c[0] = q.x; c[1] = q.y; c[2] = q.z; c[3] = q.w;
    } else {
        for (int k = 0; k < 4; k++)
            if (base + k < n) c[k] = cursor[base + k];
    }
    int s = padc(c[0]) + padc(c[1]) + padc(c[2]) + padc(c[3]);
    lds[t] = s;
    __syncthreads();
    for (int st = 1; st < 256; st <<= 1) {
        int add = (t >= st) ? lds[t - st] : 0;
        __syncthreads();
        lds[t] += add;
        __syncthreads();
    }
    int run = bsum[blockIdx.x] + ((t == 0) ? 0 : lds[t - 1]);
    if (blockIdx.x == 0 && t == 0) poffs[0] = 0;
#pragma unroll
    for (int k = 0; k < 4; k++) {
        int i = base + k;
        if (i < n) {
            int pv = padc(c[k]);
            csrsrc[run + c[k]] = i;                        // self-loop last
            for (int k2 = c[k] + 1; k2 < pv; k2++)
                csrsrc[run + k2] = n;                      // sentinel pads
            run += pv;
            poffs[i + 1] = run;
        }
    }
}

// edge scatter only: pos = poffs[dst] + rank[e]; plus end slack + sentinel row
__global__ void k_fill(const int* __restrict__ ei, const int* __restrict__ poffs,
                       const int* __restrict__ rank, int* __restrict__ csrsrc,
                       ushortT* __restrict__ hbuf, float* __restrict__ asrc,
                       int E, int n) {
    int tid = blockIdx.x * blockDim.x + threadIdx.x;
    int E4 = (E + 3) >> 2;
    if (tid < E4) {
        int i4 = tid * 4;
        if (((E & 3) == 0) && i4 + 3 < E) {
            int4 sv = *(const int4*)(ei + i4);
            int4 dv = *(const int4*)(ei + (size_t)E + i4);
            int4 rv = *(const int4*)(rank + i4);
            csrsrc[poffs[dv.x] + rv.x] = sv.x;
            csrsrc[poffs[dv.y] + rv.y] = sv.y;
            csrsrc[poffs[dv.z] + rv.z] = sv.z;
            csrsrc[poffs[dv.w] + rv.w] = sv.w;
        } else {
            for (int k = i4; k < E && k < i4 + 4; k++)
                csrsrc[poffs[ei[(size_t)E + k]] + rank[k]] = ei[k];
        }
    } else if (tid == E4) {
        int total = poffs[n];
        for (int k = 0; k < 8; k++) csrsrc[total + k] = n;   // prefetch slack
        for (int k = 0; k < D; k++) hbuf[(size_t)n * D + k] = 0;  // sentinel row
        for (int h = 0; h < H; h++) asrc[n * H + h] = -1e30f;  // weight -> 0
    }
}

// ---------------- x split: f32 -> bf16 hi/lo in A-frag order ----------------
// thread: row r = idx>>4, k-block kb = idx&15 (8 cols). Zero-fills r >= n.

__global__ __launch_bounds__(256) void k_xsplit(
    const float* __restrict__ x, ushortT* __restrict__ xh,
    ushortT* __restrict__ xl, int n, int nt16) {
    int idx = blockIdx.x * 256 + threadIdx.x;
    int r = idx >> 4;
    if (r >= nt16 * 16) return;
    int kb = idx & 15;
    float4 v0 = make_float4(0.f, 0.f, 0.f, 0.f), v1 = v0;
    if (r < n) {
        v0 = ((const float4*)(x + (size_t)r * D + kb * 8))[0];
        v1 = ((const float4*)(x + (size_t)r * D + kb * 8))[1];
    }
    int wt = r >> 4, m = r & 15, kt = kb >> 2, quad = kb & 3;
    int base = ((wt * 4 + kt) * 64 + (m + 16 * quad)) * 8;
    ushort4 h0, l0, h1, l1;
    h0.x = f2bf(v0.x); l0.x = f2bf(v0.x - bf2f(h0.x));
    h0.y = f2bf(v0.y); l0.y = f2bf(v0.y - bf2f(h0.y));
    h0.z = f2bf(v0.z); l0.z = f2bf(v0.z - bf2f(h0.z));
    h0.w = f2bf(v0.w); l0.w = f2bf(v0.w - bf2f(h0.w));
    h1.x = f2bf(v1.x); l1.x = f2bf(v1.x - bf2f(h1.x));
    h1.y = f2bf(v1.y); l1.y = f2bf(v1.y - bf2f(h1.y));
    h1.z = f2bf(v1.z); l1.z = f2bf(v1.z - bf2f(h1.z));
    h1.w = f2bf(v1.w); l1.w = f2bf(v1.w - bf2f(h1.w));
    *(ushort4*)(xh + base) = h0;
    *(ushort4*)(xh + base + 4) = h1;
    *(ushort4*)(xl + base) = l0;
    *(ushort4*)(xl + base + 4) = l1;
}

// ---------------- W prep (both layers): split-bf16, B-frag order, att folded ----

__global__ __launch_bounds__(256) void k_wprep(
    const float* __restrict__ W1, const float* __restrict__ as1,
    const float* __restrict__ ad1, const float* __restrict__ W2,
    const float* __restrict__ as2, const float* __restrict__ ad2,
    ushortT* __restrict__ wf1_hi, ushortT* __restrict__ wf1_lo,
    ushortT* __restrict__ wf2_hi, ushortT* __restrict__ wf2_lo) {
    int b = blockIdx.x;
    const float *W, *att_s, *att_d;
    ushortT *whi, *wlo;
    int idx;
    if (b < 9) {
        W = W1; att_s = as1; att_d = ad1; whi = wf1_hi; wlo = wf1_lo;
        idx = b * 256 + threadIdx.x;
    } else {
        W = W2; att_s = as2; att_d = ad2; whi = wf2_hi; wlo = wf2_lo;
        idx = (b - 9) * 256 + threadIdx.x;
    }
    if (idx >= 4 * 9 * 64) return;
    int lane = idx & 63;
    int nt = (idx >> 6) % 9;
    int kt = idx / (9 * 64);
    int quad = lane >> 4, ncol = lane & 15;
#pragma unroll
    for (int j = 0; j < 8; j++) {
        int k = kt * 32 + quad * 8 + j;
        float v;
        if (nt < 8) {
            v = W[k * D + nt * 16 + ncol];
        } else {
            const float* att = (ncol < 8) ? att_s : att_d;
            int hd = ncol & 7;
            float s = 0.f;
            for (int c = 0; c < 16; c++)
                s += W[k * D + hd * 16 + c] * att[hd * 16 + c];
            v = s;
        }
        unsigned short hi = f2bf(v);
        unsigned short lo = f2bf(v - bf2f(hi));
        whi[idx * 8 + j] = hi;
        wlo[idx * 8 + j] = lo;
    }
}

// ---------------- h = x @ W via split-bf16 MFMA; LDS-free ----------------
// One wave per 16 rows. A-frags read as lane-contiguous 16B loads from the
// pre-split x buffers; W frags from L2. No __syncthreads, no conversions.
// 9 N-tiles: 0..7 -> h columns; 8 -> [a_src | a_dst] (att folded by k_wprep).

__global__ __launch_bounds__(256) void k_gemm_att(
    const ushortT* __restrict__ xh, const ushortT* __restrict__ xl,
    const ushortT* __restrict__ wf_hi, const ushortT* __restrict__ wf_lo,
    ushortT* __restrict__ hout, float* __restrict__ as_,
    float* __restrict__ ad_, int n) {
    int t = threadIdx.x;
    int wt = blockIdx.x * 4 + (t >> 6);
    if (wt * 16 >= n) return;
    int lane = t & 63;

    f32x4 acc[9];
#pragma unroll
    for (int nt = 0; nt < 9; nt++) acc[nt] = (f32x4){0.f, 0.f, 0.f, 0.f};

#pragma unroll
    for (int kt = 0; kt < 4; kt++) {
        const ushortT* ax = xh + (size_t)((wt * 4 + kt) * 64 + lane) * 8;
        short8 a_hi = *(const short8*)ax;
        short8 a_lo = *(const short8*)(xl + (size_t)((wt * 4 + kt) * 64 + lane) * 8);
        const ushortT* bh = wf_hi + (size_t)(kt * 576 + lane) * 8;
        const ushortT* bl = wf_lo + (size_t)(kt * 576 + lane) * 8;
#pragma unroll
        for (int nt = 0; nt < 9; nt++) {
            short8 b_hi = *(const short8*)(bh + nt * 512);
            short8 b_lo = *(const short8*)(bl + nt * 512);
            acc[nt] = __builtin_amdgcn_mfma_f32_16x16x32_bf16(a_hi, b_hi, acc[nt], 0, 0, 0);
            acc[nt] = __builtin_amdgcn_mfma_f32_16x16x32_bf16(a_lo, b_hi, acc[nt], 0, 0, 0);
            acc[nt] = __builtin_amdgcn_mfma_f32_16x16x32_bf16(a_hi, b_lo, acc[nt], 0, 0, 0);
        }
    }

    // C/D layout: col = lane&15, row = (lane>>4)*4 + reg (m89-verified)
    int q = lane >> 4, ncol = lane & 15;
    int rbase = wt * 16 + q * 4;
#pragma unroll
    for (int nt = 0; nt < 8; nt++) {
#pragma unroll
        for (int reg = 0; reg < 4; reg++) {
            int r = rbase + reg;
            if (r < n) hout[(size_t)r * D + nt * 16 + ncol] = f2bf(acc[nt][reg]);
        }
    }
#pragma unroll
    for (int reg = 0; reg < 4; reg++) {
        int r = rbase + reg;
        if (r < n) {
            float v = acc[8][reg];
            if (ncol < 8) as_[r * H + ncol] = v;
            else          ad_[r * H + (ncol - 8)] = v;
        }
    }
}

// ---------------- aggregate: 2 nodes/wave, stride-1, unroll x4, no guards -------
// Lanes 0-31 = node A, 32-63 = node B; lane ll owns channels ll*4..+3.
// out_mode 0: f32 final output. out_mode 1: relu, then bf16 hi/lo split
// written in A-frag order (feeds the next LDS-free gemm directly).

__global__ __launch_bounds__(256) void k_aggregate(
    const ushortT* __restrict__ hbuf, const float* __restrict__ asrc,
    const float* __restrict__ adst, const int* __restrict__ csr,
    const int* __restrict__ poffs, const float* __restrict__ bias,
    float* __restrict__ out, ushortT* __restrict__ oh, ushortT* __restrict__ ol,
    int out_mode, int n) {
    int t = threadIdx.x;
    int d = blockIdx.x * 8 + (t >> 5);
    if (d >= n) return;
    int ll = t & 31;
    int h = ll >> 2;

    int off = poffs[d];
    int degp = poffs[d + 1] - off;   // multiple of 4, >= 4
    float adh = adst[d * H + h];

    float4 acc0 = make_float4(0.f, 0.f, 0.f, 0.f);
    float4 acc1 = make_float4(0.f, 0.f, 0.f, 0.f);
    float ssum = 0.f;

    int s0 = csr[off + 0], s1 = csr[off + 1], s2 = csr[off + 2], s3 = csr[off + 3];
    for (int j = 0; j < degp; j += 4) {
        int p0 = csr[off + j + 4], p1 = csr[off + j + 5];
        int p2 = csr[off + j + 6], p3 = csr[off + j + 7];
        float e0 = asrc[s0 * H + h] + adh;
        float e1 = asrc[s1 * H + h] + adh;
        float e2 = asrc[s2 * H + h] + adh;
        float e3 = asrc[s3 * H + h] + adh;
        ushort4 u0 = *(const ushort4*)(hbuf + (size_t)s0 * D + ll * 4);
        ushort4 u1 = *(const ushort4*)(hbuf + (size_t)s1 * D + ll * 4);
        ushort4 u2 = *(const ushort4*)(hbuf + (size_t)s2 * D + ll * 4);
        ushort4 u3 = *(const ushort4*)(hbuf + (size_t)s3 * D + ll * 4);
        float w0 = __expf(e0 > 0.f ? e0 : NEG_SLOPE * e0);
        float w1 = __expf(e1 > 0.f ? e1 : NEG_SLOPE * e1);
        float w2 = __expf(e2 > 0.f ? e2 : NEG_SLOPE * e2);
        float w3 = __expf(e3 > 0.f ? e3 : NEG_SLOPE * e3);
        ssum += (w0 + w1) + (w2 + w3);
        acc0.x += w0 * bf2f(u0.x); acc0.y += w0 * bf2f(u0.y);
        acc0.z += w0 * bf2f(u0.z); acc0.w += w0 * bf2f(u0.w);
        acc1.x += w1 * bf2f(u1.x); acc1.y += w1 * bf2f(u1.y);
        acc1.z += w1 * bf2f(u1.z); acc1.w += w1 * bf2f(u1.w);
        acc0.x += w2 * bf2f(u2.x); acc0.y += w2 * bf2f(u2.y);
        acc0.z += w2 * bf2f(u2.z); acc0.w += w2 * bf2f(u2.w);
        acc1.x += w3 * bf2f(u3.x); acc1.y += w3 * bf2f(u3.y);
        acc1.z += w3 * bf2f(u3.z); acc1.w += w3 * bf2f(u3.w);
        s0 = p0; s1 = p1; s2 = p2; s3 = p3;
    }

    float inv = 1.f / ssum;
    float4 b = ((const float4*)bias)[ll];
    float4 r;
    r.x = (acc0.x + acc1.x) * inv + b.x;
    r.y = (acc0.y + acc1.y) * inv + b.y;
    r.z = (acc0.z + acc1.z) * inv + b.z;
    r.w = (acc0.w + acc1.w) * inv + b.w;

    if (out_mode == 0) {
        ((float4*)(out + (size_t)d * D))[ll] = r;
    } else {
        r.x = fmaxf(r.x, 0.f);
        r.y = fmaxf(r.y, 0.f);
        r.z = fmaxf(r.z, 0.f);
        r.w = fmaxf(r.w, 0.f);
        // A-frag address for (row d, cols ll*4..+3)
        int wt = d >> 4, m = d & 15;
        int kt = ll >> 3, quad = (ll >> 1) & 3, j0 = (ll & 1) * 4;
        int base = ((wt * 4 + kt) * 64 + (m + 16 * quad)) * 8 + j0;
        ushort4 hv, lv;
        hv.x = f2bf(r.x); lv.x = f2bf(r.x - bf2f(hv.x));
        hv.y = f2bf(r.y); lv.y = f2bf(r.y - bf2f(hv.y));
        hv.z = f2bf(r.z); lv.z = f2bf(r.z - bf2f(hv.z));
        hv.w = f2bf(r.w); lv.w = f2bf(r.w - bf2f(hv.w));
        *(ushort4*)(oh + base) = hv;
        *(ushort4*)(ol + base) = lv;
    }
}

// ---------------- launch ----------------

extern "C" void kernel_launch(void* const* d_in, const int* in_sizes, int n_in,
                              void* d_out, int out_size, void* d_ws, size_t ws_size,
                              hipStream_t stream) {
    const float* x   = (const float*)d_in[0];
    const int*   ei  = (const int*)d_in[1];
    const float* W1  = (const float*)d_in[2];
    const float* as1 = (const float*)d_in[3];
    const float* ad1 = (const float*)d_in[4];
    const float* b1  = (const float*)d_in[5];
    const float* W2  = (const float*)d_in[6];
    const float* as2 = (const float*)d_in[7];
    const float* ad2 = (const float*)d_in[8];
    const float* b2  = (const float*)d_in[9];
    float* out = (float*)d_out;

    int N = in_sizes[0] / D;
    int E = in_sizes[1] / 2;
    int NT16 = (N + 15) / 16;
    int nb_scan = (N + SCAN_TILE - 1) / SCAN_TILE;
    const int WFN = 4 * 9 * 64 * 8;  // 18432 ushorts per wf buffer
    size_t XS = (size_t)NT16 * 2048; // ushorts per split buffer

    // workspace layout; sentinel row n in hbuf/asrc
    ushortT* hbuf = (ushortT*)d_ws;                        // (N+1)*D bf16
    ushortT* xsh  = hbuf + (size_t)(N + 1) * D;            // split hi (frag order)
    ushortT* xsl  = xsh + XS;                              // split lo
    float* asrc = (float*)(xsl + XS);                      // (N+1)*H
    float* adst = asrc + (size_t)(N + 1) * H;              // N*H
    int*   poffs  = (int*)(adst + (size_t)N * H);          // N+1
    int*   cursor = poffs + ((N + 1 + 3) & ~3);            // N (16B-aligned)
    int*   bsum   = cursor + ((N + 3) & ~3);               // nb_scan
    int*   rank   = bsum + ((nb_scan + 3) & ~3);           // E
    int*   csrsrc = rank + ((E + 3) & ~3);                 // E + 4N + 8
    ushortT* wf1_hi = (ushortT*)(csrsrc + ((E + 4 * N + 8 + 3) & ~3));
    ushortT* wf1_lo = wf1_hi + WFN;
    ushortT* wf2_hi = wf1_lo + WFN;
    ushortT* wf2_lo = wf2_hi + WFN;

    hipMemsetAsync(cursor, 0, (size_t)N * sizeof(int), stream);

    int nb;
    nb = ((E + 3) / 4 + 255) / 256;
    k_hist<<<nb, 256, 0, stream>>>(ei, cursor, rank, E, N);
    k_scan_partial<<<nb_scan, 256, 0, stream>>>(cursor, bsum, N);
    k_scan_bsum<<<1, 64, 0, stream>>>(bsum, nb_scan);
    k_scan_final<<<nb_scan, 256, 0, stream>>>(cursor, poffs, bsum, csrsrc, N);
    nb = ((E + 3) / 4 + 1 + 255) / 256;
    k_fill<<<nb, 256, 0, stream>>>(ei, poffs, rank, csrsrc, hbuf, asrc, E, N);

    k_wprep<<<18, 256, 0, stream>>>(W1, as1, ad1, W2, as2, ad2,
                                    wf1_hi, wf1_lo, wf2_hi, wf2_lo);
    k_xsplit<<<NT16, 256, 0, stream>>>(x, xsh, xsl, N, NT16);

    int gb = (NT16 + 3) / 4;
    int ab = (N + 7) / 8;
    // layer 1
    k_gemm_att<<<gb, 256, 0, stream>>>(xsh, xsl, wf1_hi, wf1_lo, hbuf, asrc, adst, N);
    k_aggregate<<<ab, 256, 0, stream>>>(hbuf, asrc, adst, csrsrc, poffs, b1,
                                        out, xsh, xsl, 1, N);
    // layer 2 (reads split frags produced by aggregate 1)
    k_gemm_att<<<gb, 256, 0, stream>>>(xsh, xsl, wf2_hi, wf2_lo, hbuf, asrc, adst, N);
    k_aggregate<<<ab, 256, 0, stream>>>(hbuf, asrc, adst, csrsrc, poffs, b2,
                                        out, xsh, xsl, 0, N);
}

// Round 10
// 254.955 us; speedup vs baseline: 1.0893x; 1.0893x over previous
//
#include <hip/hip_runtime.h>
#include <math.h>

#define D 128
#define H 8
#define C 16
#define NEG_SLOPE 0.2f
#define SCAN_TILE 1024  // elements per scan block (256 thr x 4)

typedef unsigned short ushortT;
typedef __attribute__((ext_vector_type(8))) short short8;
typedef __attribute__((ext_vector_type(4))) float f32x4;

// bf16 <-> f32 helpers (RNE pack; no NaN inputs here)
__device__ __forceinline__ float bf2f(unsigned short v) {
    union { unsigned int i; float f; } c;
    c.i = ((unsigned int)v) << 16;
    return c.f;
}
__device__ __forceinline__ unsigned short f2bf(float f) {
    union { float f; unsigned int i; } c;
    c.f = f;
    unsigned int lsb = (c.i >> 16) & 1u;
    c.i += 0x7fffu + lsb;
    return (unsigned short)(c.i >> 16);
}

// padded count per node = (cnt + 1 self-loop + 3) & ~3  (>= 4, multiple of 4)
__device__ __forceinline__ int padc(int c) { return (c + 4) & ~3; }

// A-frag address for element (row r, col k):
// wt=r>>4, m=r&15, kt=k>>5, quad=(k>>3)&3, j=k&7, lane=m+16*quad
// addr = ((wt*4+kt)*64 + lane)*8 + j     (2048 ushorts per 16x128 tile)

// ---------------- fused prep: hist | wprep | xsplit (independent) ----------------

__device__ __forceinline__ void hist_part(
    int tid, const int* __restrict__ ei, int* cursor, int* __restrict__ rank,
    int E) {
    int i4 = tid * 4;
    if (((E & 3) == 0) && i4 + 3 < E) {
        int4 dv = *(const int4*)(ei + (size_t)E + i4);
        int4 r;
        r.x = atomicAdd(cursor + dv.x, 1);
        r.y = atomicAdd(cursor + dv.y, 1);
        r.z = atomicAdd(cursor + dv.z, 1);
        r.w = atomicAdd(cursor + dv.w, 1);
        *(int4*)(rank + i4) = r;
    } else {
        for (int k = i4; k < E && k < i4 + 4; k++)
            rank[k] = atomicAdd(cursor + ei[(size_t)E + k], 1);
    }
}

__device__ __forceinline__ void wprep_part(
    int b2, int t, const float* __restrict__ W1, const float* __restrict__ as1,
    const float* __restrict__ ad1, const float* __restrict__ W2,
    const float* __restrict__ as2, const float* __restrict__ ad2,
    ushortT* __restrict__ wf1_hi, ushortT* __restrict__ wf1_lo,
    ushortT* __restrict__ wf2_hi, ushortT* __restrict__ wf2_lo) {
    const float *W, *att_s, *att_d;
    ushortT *whi, *wlo;
    int idx;
    if (b2 < 9) {
        W = W1; att_s = as1; att_d = ad1; whi = wf1_hi; wlo = wf1_lo;
        idx = b2 * 256 + t;
    } else {
        W = W2; att_s = as2; att_d = ad2; whi = wf2_hi; wlo = wf2_lo;
        idx = (b2 - 9) * 256 + t;
    }
    if (idx >= 4 * 9 * 64) return;
    int lane = idx & 63;
    int nt = (idx >> 6) % 9;
    int kt = idx / (9 * 64);
    int quad = lane >> 4, ncol = lane & 15;
#pragma unroll
    for (int j = 0; j < 8; j++) {
        int k = kt * 32 + quad * 8 + j;
        float v;
        if (nt < 8) {
            v = W[k * D + nt * 16 + ncol];
        } else {
            const float* att = (ncol < 8) ? att_s : att_d;
            int hd = ncol & 7;
            float s = 0.f;
            for (int c = 0; c < 16; c++)
                s += W[k * D + hd * 16 + c] * att[hd * 16 + c];
            v = s;
        }
        unsigned short hi = f2bf(v);
        unsigned short lo = f2bf(v - bf2f(hi));
        whi[idx * 8 + j] = hi;
        wlo[idx * 8 + j] = lo;
    }
}

__device__ __forceinline__ void xsplit_part(
    int idx, const float* __restrict__ x, ushortT* __restrict__ xh,
    ushortT* __restrict__ xl, int n, int nt16) {
    int r = idx >> 4;
    if (r >= nt16 * 16) return;
    int kb = idx & 15;
    float4 v0 = make_float4(0.f, 0.f, 0.f, 0.f), v1 = v0;
    if (r < n) {
        v0 = ((const float4*)(x + (size_t)r * D + kb * 8))[0];
        v1 = ((const float4*)(x + (size_t)r * D + kb * 8))[1];
    }
    int wt = r >> 4, m = r & 15, kt = kb >> 2, quad = kb & 3;
    int base = ((wt * 4 + kt) * 64 + (m + 16 * quad)) * 8;
    ushort4 h0, l0, h1, l1;
    h0.x = f2bf(v0.x); l0.x = f2bf(v0.x - bf2f(h0.x));
    h0.y = f2bf(v0.y); l0.y = f2bf(v0.y - bf2f(h0.y));
    h0.z = f2bf(v0.z); l0.z = f2bf(v0.z - bf2f(h0.z));
    h0.w = f2bf(v0.w); l0.w = f2bf(v0.w - bf2f(h0.w));
    h1.x = f2bf(v1.x); l1.x = f2bf(v1.x - bf2f(h1.x));
    h1.y = f2bf(v1.y); l1.y = f2bf(v1.y - bf2f(h1.y));
    h1.z = f2bf(v1.z); l1.z = f2bf(v1.z - bf2f(h1.z));
    h1.w = f2bf(v1.w); l1.w = f2bf(v1.w - bf2f(h1.w));
    *(ushort4*)(xh + base) = h0;
    *(ushort4*)(xh + base + 4) = h1;
    *(ushort4*)(xl + base) = l0;
    *(ushort4*)(xl + base + 4) = l1;
}

__global__ __launch_bounds__(256) void k_prep(
    const int* __restrict__ ei, int* cursor, int* __restrict__ rank, int E,
    const float* __restrict__ x, ushortT* __restrict__ xh,
    ushortT* __restrict__ xl, int n, int nt16,
    const float* __restrict__ W1, const float* __restrict__ as1,
    const float* __restrict__ ad1, const float* __restrict__ W2,
    const float* __restrict__ as2, const float* __restrict__ ad2,
    ushortT* __restrict__ wf1_hi, ushortT* __restrict__ wf1_lo,
    ushortT* __restrict__ wf2_hi, ushortT* __restrict__ wf2_lo, int nbh) {
    int b = blockIdx.x;
    int t = threadIdx.x;
    if (b < nbh) {
        hist_part(b * 256 + t, ei, cursor, rank, E);
    } else if (b < nbh + 18) {
        wprep_part(b - nbh, t, W1, as1, ad1, W2, as2, ad2,
                   wf1_hi, wf1_lo, wf2_hi, wf2_lo);
    } else {
        xsplit_part((b - nbh - 18) * 256 + t, x, xh, xl, n, nt16);
    }
}

// ---------------- single-pass decoupled-lookback scan + self-loop/pads ----------
// 49 blocks, all co-resident on 256 CUs -> spin-free-deadlock guaranteed.
// sstate[b] = tile_total | (1<<30), device-scope release; predecessors polled
// with device-scope relaxed loads. Also writes poffs and places self-loops +
// sentinel pads (was scan_final).

__global__ __launch_bounds__(256) void k_scan_lb(
    const int* __restrict__ cursor, int* __restrict__ poffs,
    int* __restrict__ sstate, int* __restrict__ csrsrc, int n) {
    __shared__ int lds[256];
    __shared__ int bprefix;
    int t = threadIdx.x;
    int b = blockIdx.x;
    int base = b * SCAN_TILE + t * 4;
    int c[4] = {0, 0, 0, 0};
    if (base + 3 < n) {
        int4 q = *(const int4*)(cursor + base);
        c[0] = q.x; c[1] = q.y; c[2] = q.z; c[3] = q.w;
    } else {
        for (int k = 0; k < 4; k++)
            if (base + k < n) c[k] = cursor[base + k];
    }
    int s = padc(c[0]) + padc(c[1]) + padc(c[2]) + padc(c[3]);
    lds[t] = s;
    __syncthreads();
    for (int st = 1; st < 256; st <<= 1) {
        int add = (t >= st) ? lds[t - st] : 0;
        __syncthreads();
        lds[t] += add;
        __syncthreads();
    }
    if (t == 0)
        __hip_atomic_store(&sstate[b], lds[255] | (1 << 30),
                           __ATOMIC_RELEASE, __HIP_MEMORY_SCOPE_AGENT);
    if (t < 64) {
        int v = 0;
        if (t < b) {
            int x;
            do {
                x = __hip_atomic_load(&sstate[t], __ATOMIC_RELAXED,
                                      __HIP_MEMORY_SCOPE_AGENT);
            } while (!(x & (1 << 30)));
            v = x & 0x3FFFFFFF;
        }
#pragma unroll
        for (int o = 32; o > 0; o >>= 1) v += __shfl_down(v, o);
        if (t == 0) bprefix = v;
    }
    __syncthreads();
    int run = bprefix + ((t == 0) ? 0 : lds[t - 1]);
    if (b == 0 && t == 0) poffs[0] = 0;
#pragma unroll
    for (int k = 0; k < 4; k++) {
        int i = base + k;
        if (i < n) {
            int pv = padc(c[k]);
            csrsrc[run + c[k]] = i;                        // self-loop last
            for (int k2 = c[k] + 1; k2 < pv; k2++)
                csrsrc[run + k2] = n;                      // sentinel pads
            run += pv;
            poffs[i + 1] = run;
        }
    }
}

// ---------------- gemm wave body (split-bf16 MFMA, LDS-free) ----------------

__device__ __forceinline__ void gemm_wave(
    int wt, int lane, const ushortT* __restrict__ xh,
    const ushortT* __restrict__ xl, const ushortT* __restrict__ wf_hi,
    const ushortT* __restrict__ wf_lo, ushortT* __restrict__ hout,
    float* __restrict__ as_, float* __restrict__ ad_, int n) {
    f32x4 acc[9];
#pragma unroll
    for (int nt = 0; nt < 9; nt++) acc[nt] = (f32x4){0.f, 0.f, 0.f, 0.f};

#pragma unroll
    for (int kt = 0; kt < 4; kt++) {
        short8 a_hi = *(const short8*)(xh + (size_t)((wt * 4 + kt) * 64 + lane) * 8);
        short8 a_lo = *(const short8*)(xl + (size_t)((wt * 4 + kt) * 64 + lane) * 8);
        const ushortT* bh = wf_hi + (size_t)(kt * 576 + lane) * 8;
        const ushortT* bl = wf_lo + (size_t)(kt * 576 + lane) * 8;
#pragma unroll
        for (int nt = 0; nt < 9; nt++) {
            short8 b_hi = *(const short8*)(bh + nt * 512);
            short8 b_lo = *(const short8*)(bl + nt * 512);
            acc[nt] = __builtin_amdgcn_mfma_f32_16x16x32_bf16(a_hi, b_hi, acc[nt], 0, 0, 0);
            acc[nt] = __builtin_amdgcn_mfma_f32_16x16x32_bf16(a_lo, b_hi, acc[nt], 0, 0, 0);
            acc[nt] = __builtin_amdgcn_mfma_f32_16x16x32_bf16(a_hi, b_lo, acc[nt], 0, 0, 0);
        }
    }

    // C/D layout: col = lane&15, row = (lane>>4)*4 + reg (m89-verified)
    int q = lane >> 4, ncol = lane & 15;
    int rbase = wt * 16 + q * 4;
#pragma unroll
    for (int nt = 0; nt < 8; nt++) {
#pragma unroll
        for (int reg = 0; reg < 4; reg++) {
            int r = rbase + reg;
            if (r < n) hout[(size_t)r * D + nt * 16 + ncol] = f2bf(acc[nt][reg]);
        }
    }
#pragma unroll
    for (int reg = 0; reg < 4; reg++) {
        int r = rbase + reg;
        if (r < n) {
            float v = acc[8][reg];
            if (ncol < 8) as_[r * H + ncol] = v;
            else          ad_[r * H + (ncol - 8)] = v;
        }
    }
}

// ---------------- fused: edge scatter (fill) | layer-1 gemm ----------------
// fill depends on scan; gemm depends on prep -- both satisfied here. The
// scatter's VMEM path overlaps the gemm's MFMA path.

__global__ __launch_bounds__(256) void k_fillgemm(
    const int* __restrict__ ei, const int* __restrict__ poffs,
    const int* __restrict__ rank, int* __restrict__ csrsrc,
    ushortT* __restrict__ hbuf_s, float* __restrict__ asrc_s, int E,
    const ushortT* __restrict__ xh, const ushortT* __restrict__ xl,
    const ushortT* __restrict__ wf_hi, const ushortT* __restrict__ wf_lo,
    ushortT* __restrict__ hout, float* __restrict__ as_,
    float* __restrict__ ad_, int n, int gb) {
    int b = blockIdx.x;
    int t = threadIdx.x;
    if (b < gb) {
        int wt = b * 4 + (t >> 6);
        if (wt * 16 < n)
            gemm_wave(wt, t & 63, xh, xl, wf_hi, wf_lo, hout, as_, ad_, n);
        return;
    }
    int tid = (b - gb) * 256 + t;
    int E4 = (E + 3) >> 2;
    if (tid < E4) {
        int i4 = tid * 4;
        if (((E & 3) == 0) && i4 + 3 < E) {
            int4 sv = *(const int4*)(ei + i4);
            int4 dv = *(const int4*)(ei + (size_t)E + i4);
            int4 rv = *(const int4*)(rank + i4);
            csrsrc[poffs[dv.x] + rv.x] = sv.x;
            csrsrc[poffs[dv.y] + rv.y] = sv.y;
            csrsrc[poffs[dv.z] + rv.z] = sv.z;
            csrsrc[poffs[dv.w] + rv.w] = sv.w;
        } else {
            for (int k = i4; k < E && k < i4 + 4; k++)
                csrsrc[poffs[ei[(size_t)E + k]] + rank[k]] = ei[k];
        }
    } else if (tid == E4) {
        int total = poffs[n];
        for (int k = 0; k < 8; k++) csrsrc[total + k] = n;        // slack
        for (int k = 0; k < D; k++) hbuf_s[(size_t)n * D + k] = 0; // sentinel row
        for (int h = 0; h < H; h++) asrc_s[n * H + h] = -1e30f;    // weight -> 0
    }
}

// ---------------- standalone gemm (layer 2) ----------------

__global__ __launch_bounds__(256) void k_gemm_att(
    const ushortT* __restrict__ xh, const ushortT* __restrict__ xl,
    const ushortT* __restrict__ wf_hi, const ushortT* __restrict__ wf_lo,
    ushortT* __restrict__ hout, float* __restrict__ as_,
    float* __restrict__ ad_, int n) {
    int t = threadIdx.x;
    int wt = blockIdx.x * 4 + (t >> 6);
    if (wt * 16 >= n) return;
    gemm_wave(wt, t & 63, xh, xl, wf_hi, wf_lo, hout, as_, ad_, n);
}

// ---------------- aggregate: 2 nodes/wave, stride-1, unroll x4, no guards -------
// Lanes 0-31 = node A, 32-63 = node B; lane ll owns channels ll*4..+3.
// out_mode 0: f32 final output. out_mode 1: relu, then bf16 hi/lo split
// written in A-frag order (feeds the next LDS-free gemm directly).

__global__ __launch_bounds__(256) void k_aggregate(
    const ushortT* __restrict__ hbuf, const float* __restrict__ asrc,
    const float* __restrict__ adst, const int* __restrict__ csr,
    const int* __restrict__ poffs, const float* __restrict__ bias,
    float* __restrict__ out, ushortT* __restrict__ oh, ushortT* __restrict__ ol,
    int out_mode, int n) {
    int t = threadIdx.x;
    int d = blockIdx.x * 8 + (t >> 5);
    if (d >= n) return;
    int ll = t & 31;
    int h = ll >> 2;

    int off = poffs[d];
    int degp = poffs[d + 1] - off;   // multiple of 4, >= 4
    float adh = adst[d * H + h];

    float4 acc0 = make_float4(0.f, 0.f, 0.f, 0.f);
    float4 acc1 = make_float4(0.f, 0.f, 0.f, 0.f);
    float ssum = 0.f;

    int s0 = csr[off + 0], s1 = csr[off + 1], s2 = csr[off + 2], s3 = csr[off + 3];
    for (int j = 0; j < degp; j += 4) {
        int p0 = csr[off + j + 4], p1 = csr[off + j + 5];
        int p2 = csr[off + j + 6], p3 = csr[off + j + 7];
        float e0 = asrc[s0 * H + h] + adh;
        float e1 = asrc[s1 * H + h] + adh;
        float e2 = asrc[s2 * H + h] + adh;
        float e3 = asrc[s3 * H + h] + adh;
        ushort4 u0 = *(const ushort4*)(hbuf + (size_t)s0 * D + ll * 4);
        ushort4 u1 = *(const ushort4*)(hbuf + (size_t)s1 * D + ll * 4);
        ushort4 u2 = *(const ushort4*)(hbuf + (size_t)s2 * D + ll * 4);
        ushort4 u3 = *(const ushort4*)(hbuf + (size_t)s3 * D + ll * 4);
        float w0 = __expf(e0 > 0.f ? e0 : NEG_SLOPE * e0);
        float w1 = __expf(e1 > 0.f ? e1 : NEG_SLOPE * e1);
        float w2 = __expf(e2 > 0.f ? e2 : NEG_SLOPE * e2);
        float w3 = __expf(e3 > 0.f ? e3 : NEG_SLOPE * e3);
        ssum += (w0 + w1) + (w2 + w3);
        acc0.x += w0 * bf2f(u0.x); acc0.y += w0 * bf2f(u0.y);
        acc0.z += w0 * bf2f(u0.z); acc0.w += w0 * bf2f(u0.w);
        acc1.x += w1 * bf2f(u1.x); acc1.y += w1 * bf2f(u1.y);
        acc1.z += w1 * bf2f(u1.z); acc1.w += w1 * bf2f(u1.w);
        acc0.x += w2 * bf2f(u2.x); acc0.y += w2 * bf2f(u2.y);
        acc0.z += w2 * bf2f(u2.z); acc0.w += w2 * bf2f(u2.w);
        acc1.x += w3 * bf2f(u3.x); acc1.y += w3 * bf2f(u3.y);
        acc1.z += w3 * bf2f(u3.z); acc1.w += w3 * bf2f(u3.w);
        s0 = p0; s1 = p1; s2 = p2; s3 = p3;
    }

    float inv = 1.f / ssum;
    float4 b = ((const float4*)bias)[ll];
    float4 r;
    r.x = (acc0.x + acc1.x) * inv + b.x;
    r.y = (acc0.y + acc1.y) * inv + b.y;
    r.z = (acc0.z + acc1.z) * inv + b.z;
    r.w = (acc0.w + acc1.w) * inv + b.w;

    if (out_mode == 0) {
        ((float4*)(out + (size_t)d * D))[ll] = r;
    } else {
        r.x = fmaxf(r.x, 0.f);
        r.y = fmaxf(r.y, 0.f);
        r.z = fmaxf(r.z, 0.f);
        r.w = fmaxf(r.w, 0.f);
        // A-frag address for (row d, cols ll*4..+3)
        int wt = d >> 4, m = d & 15;
        int kt = ll >> 3, quad = (ll >> 1) & 3, j0 = (ll & 1) * 4;
        int base = ((wt * 4 + kt) * 64 + (m + 16 * quad)) * 8 + j0;
        ushort4 hv, lv;
        hv.x = f2bf(r.x); lv.x = f2bf(r.x - bf2f(hv.x));
        hv.y = f2bf(r.y); lv.y = f2bf(r.y - bf2f(hv.y));
        hv.z = f2bf(r.z); lv.z = f2bf(r.z - bf2f(hv.z));
        hv.w = f2bf(r.w); lv.w = f2bf(r.w - bf2f(hv.w));
        *(ushort4*)(oh + base) = hv;
        *(ushort4*)(ol + base) = lv;
    }
}

// ---------------- launch ----------------

extern "C" void kernel_launch(void* const* d_in, const int* in_sizes, int n_in,
                              void* d_out, int out_size, void* d_ws, size_t ws_size,
                              hipStream_t stream) {
    const float* x   = (const float*)d_in[0];
    const int*   ei  = (const int*)d_in[1];
    const float* W1  = (const float*)d_in[2];
    const float* as1 = (const float*)d_in[3];
    const float* ad1 = (const float*)d_in[4];
    const float* b1  = (const float*)d_in[5];
    const float* W2  = (const float*)d_in[6];
    const float* as2 = (const float*)d_in[7];
    const float* ad2 = (const float*)d_in[8];
    const float* b2  = (const float*)d_in[9];
    float* out = (float*)d_out;

    int N = in_sizes[0] / D;
    int E = in_sizes[1] / 2;
    int NT16 = (N + 15) / 16;
    int nb_scan = (N + SCAN_TILE - 1) / SCAN_TILE;   // <= 64 assumed (N <= 64K)
    const int WFN = 4 * 9 * 64 * 8;  // 18432 ushorts per wf buffer
    size_t XS = (size_t)NT16 * 2048; // ushorts per split buffer
    int E4 = (E + 3) >> 2;

    // workspace layout; sentinel row n in hbuf/asrc
    ushortT* hbuf = (ushortT*)d_ws;                        // (N+1)*D bf16
    ushortT* xsh  = hbuf + (size_t)(N + 1) * D;            // split hi (frag order)
    ushortT* xsl  = xsh + XS;                              // split lo
    float* asrc = (float*)(xsl + XS);                      // (N+1)*H
    float* adst = asrc + (size_t)(N + 1) * H;              // N*H
    int*   poffs  = (int*)(adst + (size_t)N * H);          // N+1
    int*   cursor = poffs + ((N + 1 + 3) & ~3);            // N (16B-aligned)
    int*   sstate = cursor + ((N + 3) & ~3);               // 64 (lookback state)
    int*   rank   = sstate + 64;                           // E
    int*   csrsrc = rank + ((E + 3) & ~3);                 // E + 4N + 8
    ushortT* wf1_hi = (ushortT*)(csrsrc + ((E + 4 * N + 8 + 3) & ~3));
    ushortT* wf1_lo = wf1_hi + WFN;
    ushortT* wf2_hi = wf1_lo + WFN;
    ushortT* wf2_lo = wf2_hi + WFN;

    // zero cursor + lookback state in one memset
    hipMemsetAsync(cursor, 0, (size_t)(((N + 3) & ~3) + 64) * sizeof(int), stream);

    int nbh = (E4 + 255) / 256;
    int nbx = (NT16 * 16 * 16 + 255) / 256;  // xsplit: 16 threads/row
    k_prep<<<nbh + 18 + nbx, 256, 0, stream>>>(
        ei, cursor, rank, E, x, xsh, xsl, N, NT16,
        W1, as1, ad1, W2, as2, ad2, wf1_hi, wf1_lo, wf2_hi, wf2_lo, nbh);

    k_scan_lb<<<nb_scan, 256, 0, stream>>>(cursor, poffs, sstate, csrsrc, N);

    int gb = (NT16 + 3) / 4;
    int nf = (E4 + 1 + 255) / 256;
    int ab = (N + 7) / 8;
    // layer 1: fill | gemm fused
    k_fillgemm<<<gb + nf, 256, 0, stream>>>(
        ei, poffs, rank, csrsrc, hbuf, asrc, E,
        xsh, xsl, wf1_hi, wf1_lo, hbuf, asrc, adst, N, gb);
    k_aggregate<<<ab, 256, 0, stream>>>(hbuf, asrc, adst, csrsrc, poffs, b1,
                                        out, xsh, xsl, 1, N);
    // layer 2 (reads split frags produced by aggregate 1)
    k_gemm_att<<<gb, 256, 0, stream>>>(xsh, xsl, wf2_hi, wf2_lo, hbuf, asrc, adst, N);
    k_aggregate<<<ab, 256, 0, stream>>>(hbuf, asrc, adst, csrsrc, poffs, b2,
                                        out, xsh, xsl, 0, N);
}